// Round 2
// baseline (1598.173 us; speedup 1.0000x reference)
//
#include <hip/hip_runtime.h>

#define NQ 12
#define NL 6
#define NC 10

__device__ __forceinline__ float shx(float v, int m) { return __shfl_xor(v, m, 64); }

// ---- Rot on a local qubit: M = bit mask within the 6 local bits ----
template<int M>
__device__ __forceinline__ void rot_local(float (&sr)[64], float (&si)[64],
    float u00r, float u00i, float u01r, float u01i,
    float u10r, float u10i, float u11r, float u11i)
{
    #pragma unroll
    for (int p = 0; p < 32; ++p) {
        const int i0 = ((p & ~(M - 1)) << 1) | (p & (M - 1));
        const int i1 = i0 | M;
        float a0r = sr[i0], a0i = si[i0];
        float a1r = sr[i1], a1i = si[i1];
        sr[i0] = u00r * a0r - u00i * a0i + u01r * a1r - u01i * a1i;
        si[i0] = u00r * a0i + u00i * a0r + u01r * a1i + u01i * a1r;
        sr[i1] = u10r * a0r - u10i * a0i + u11r * a1r - u11i * a1i;
        si[i1] = u10r * a0i + u10i * a0r + u11r * a1i + u11i * a1r;
    }
}

// ---- Rot on a lane qubit: LB = lane bit index 0..5 ----
template<int LB>
__device__ __forceinline__ void rot_lane(float (&sr)[64], float (&si)[64], int lane,
    float u00r, float u00i, float u01r, float u01i,
    float u10r, float u10i, float u11r, float u11i)
{
    const bool hi = (lane >> LB) & 1;
    const float cmr = hi ? u11r : u00r, cmi = hi ? u11i : u00i;
    const float cor = hi ? u10r : u01r, coi = hi ? u10i : u01i;
    #pragma unroll
    for (int i = 0; i < 64; ++i) {
        float orr = shx(sr[i], 1 << LB);
        float oii = shx(si[i], 1 << LB);
        float mr = sr[i], mi = si[i];
        sr[i] = cmr * mr - cmi * mi + cor * orr - coi * oii;
        si[i] = cmr * mi + cmi * mr + cor * oii + coi * orr;
    }
}

// ---- CNOT: BC/BT = bit positions (0..11) of control/target; <6 local, >=6 lane ----
template<int BC, int BT>
__device__ __forceinline__ void cnot(float (&sr)[64], float (&si)[64], int lane)
{
    if constexpr (BC < 6 && BT < 6) {
        // both local: compile-time register permutation (free)
        constexpr int CM = 1 << BC, TM = 1 << BT;
        #pragma unroll
        for (int i = 0; i < 64; ++i) {
            if ((i & CM) && !(i & TM)) {
                const int j = i | TM;
                float tr = sr[i]; sr[i] = sr[j]; sr[j] = tr;
                float ti = si[i]; si[i] = si[j]; si[j] = ti;
            }
        }
    } else if constexpr (BC < 6 && BT >= 6) {
        // control local, target lane: amps with control bit set swap across lanes
        constexpr int CM = 1 << BC;
        constexpr int LM = 1 << (BT - 6);
        #pragma unroll
        for (int i = 0; i < 64; ++i) {
            if (i & CM) {
                sr[i] = shx(sr[i], LM);
                si[i] = shx(si[i], LM);
            }
        }
    } else if constexpr (BC >= 6 && BT < 6) {
        // control lane, target local: lanes with control bit swap local pairs
        constexpr int TM = 1 << BT;
        const bool c = (lane >> (BC - 6)) & 1;
        #pragma unroll
        for (int i = 0; i < 64; ++i) {
            if (!(i & TM)) {
                const int j = i | TM;
                float ar = sr[i], br = sr[j];
                sr[i] = c ? br : ar; sr[j] = c ? ar : br;
                float ai = si[i], bi = si[j];
                si[i] = c ? bi : ai; si[j] = c ? ai : bi;
            }
        }
    } else {
        // both lane
        constexpr int LM = 1 << (BT - 6);
        const bool c = (lane >> (BC - 6)) & 1;
        #pragma unroll
        for (int i = 0; i < 64; ++i) {
            float pr = shx(sr[i], LM);
            float pi = shx(si[i], LM);
            sr[i] = c ? pr : sr[i];
            si[i] = c ? pi : si[i];
        }
    }
}

// ---- CNOT ring with range R, q ascending (order must match reference) ----
template<int R, int Q>
__device__ __forceinline__ void ring(float (&sr)[64], float (&si)[64], int lane)
{
    if constexpr (Q < NQ) {
        constexpr int T = (Q + R) % NQ;
        cnot<NQ - 1 - Q, NQ - 1 - T>(sr, si, lane);
        ring<R, Q + 1>(sr, si, lane);
    }
}

// ---- all 12 Rot gates of one layer; g points at this layer's 12x8 coeffs in LDS ----
template<int Q>
__device__ __forceinline__ void rots(float (&sr)[64], float (&si)[64], int lane, const float* g)
{
    if constexpr (Q < NQ) {
        const float* gg = g + Q * 8;
        constexpr int BIT = NQ - 1 - Q;
        if constexpr (BIT < 6)
            rot_local<(1 << BIT)>(sr, si, gg[0], gg[1], gg[2], gg[3], gg[4], gg[5], gg[6], gg[7]);
        else
            rot_lane<BIT - 6>(sr, si, lane, gg[0], gg[1], gg[2], gg[3], gg[4], gg[5], gg[6], gg[7]);
        rots<Q + 1>(sr, si, lane, g);
    }
}

__global__ __launch_bounds__(64) void qsim_reg_kernel(
    const float* __restrict__ x,     // [B, NQ]
    const float* __restrict__ qp,    // [NL, NQ, 3]
    const float* __restrict__ fc_w,  // [NC, NQ]
    const float* __restrict__ fc_b,  // [NC]
    float* __restrict__ out,         // [B, NC]
    int B)
{
    __shared__ float gm[NL * NQ * 8];
    __shared__ float csx[NQ], ssx[NQ];

    const int lane = threadIdx.x;
    const int b = blockIdx.x;
    if (b >= B) return;

    // per-block gate matrices (uniform across blocks; ~0.2% of work)
    for (int g = lane; g < NL * NQ; g += 64) {
        float phi = qp[g * 3 + 0];
        float th  = qp[g * 3 + 1];
        float om  = qp[g * 3 + 2];
        float st_, ct, sa, ca, sb, cb;
        sincosf(0.5f * th, &st_, &ct);
        sincosf(0.5f * (phi + om), &sa, &ca);
        sincosf(0.5f * (phi - om), &sb, &cb);
        float* G = &gm[g * 8];
        G[0] =  ca * ct;  G[1] = -sa * ct;   // U00
        G[2] = -cb * st_; G[3] = -sb * st_;  // U01
        G[4] =  cb * st_; G[5] = -sb * st_;  // U10
        G[6] =  ca * ct;  G[7] =  sa * ct;   // U11
    }
    if (lane < NQ) {
        float s, c;
        sincosf(0.5f * x[b * NQ + lane], &s, &c);
        csx[lane] = c; ssx[lane] = s;
    }
    __syncthreads();

    // ---- state in registers: index = lane*64 + local ----
    // bit position p: p in [0,5] -> local bit (qubit 11-p); p in [6,11] -> lane bit p-6 (qubit 5-(p-6))
    float sr[64], si_[64];
    {
        float lf = 1.0f;
        #pragma unroll
        for (int k = 0; k < 6; ++k)
            lf *= ((lane >> k) & 1) ? ssx[5 - k] : csx[5 - k];
        sr[0] = lf;
        #pragma unroll
        for (int j = 0; j < 6; ++j) {
            const int M = 1 << j;
            const float cq = csx[11 - j], sq = ssx[11 - j];
            #pragma unroll
            for (int i = 0; i < M; ++i) {
                sr[i + M] = sr[i] * sq;
                sr[i]     = sr[i] * cq;
            }
        }
        #pragma unroll
        for (int i = 0; i < 64; ++i) si_[i] = 0.0f;
    }

    // ---- layers ----
    #pragma unroll 1
    for (int l = 0; l < NL; ++l) {
        rots<0>(sr, si_, lane, &gm[l * NQ * 8]);
        switch (l) {   // r = l+1, compile-time per case
            case 0: ring<1, 0>(sr, si_, lane); break;
            case 1: ring<2, 0>(sr, si_, lane); break;
            case 2: ring<3, 0>(sr, si_, lane); break;
            case 3: ring<4, 0>(sr, si_, lane); break;
            case 4: ring<5, 0>(sr, si_, lane); break;
            default: ring<6, 0>(sr, si_, lane); break;
        }
    }

    // ---- PauliZ expvals ----
    float S = 0.0f;
    float zloc[6];
    #pragma unroll
    for (int j = 0; j < 6; ++j) zloc[j] = 0.0f;
    #pragma unroll
    for (int i = 0; i < 64; ++i) {
        float p2 = sr[i] * sr[i] + si_[i] * si_[i];
        S += p2;
        #pragma unroll
        for (int j = 0; j < 6; ++j)
            zloc[j] += ((i >> j) & 1) ? -p2 : p2;
    }

    float z[NQ];
    // local qubits: cross-lane total of signed sums
    #pragma unroll
    for (int j = 0; j < 6; ++j) {
        float v = zloc[j];
        #pragma unroll
        for (int st = 1; st < 64; st <<= 1) v += shx(v, st);
        z[11 - j] = v;
    }
    // lane qubits: sign by lane bit, then butterfly
    #pragma unroll
    for (int k = 0; k < 6; ++k) {
        float v = ((lane >> k) & 1) ? -S : S;
        #pragma unroll
        for (int st = 1; st < 64; st <<= 1) v += shx(v, st);
        z[5 - k] = v;
    }

    // ---- FC ----
    if (lane < NC) {
        float acc = fc_b[lane];
        #pragma unroll
        for (int q = 0; q < NQ; ++q) acc += fc_w[lane * NQ + q] * z[q];
        out[b * NC + lane] = acc;
    }
}

extern "C" void kernel_launch(void* const* d_in, const int* in_sizes, int n_in,
                              void* d_out, int out_size, void* d_ws, size_t ws_size,
                              hipStream_t stream) {
    const float* x    = (const float*)d_in[0];
    const float* qp   = (const float*)d_in[1];
    const float* fc_w = (const float*)d_in[2];
    const float* fc_b = (const float*)d_in[3];
    float* out = (float*)d_out;
    int B = in_sizes[0] / NQ;
    qsim_reg_kernel<<<B, 64, 0, stream>>>(x, qp, fc_w, fc_b, out, B);
}

// Round 3
// 402.795 us; speedup vs baseline: 3.9677x; 3.9677x over previous
//
#include <hip/hip_runtime.h>

#define NQ 12
#define NL 6
#define NC 10
#define DIM 4096
#define TPB 256

struct PassData { unsigned v[4]; unsigned r[4]; unsigned lm[4]; };  // 48 B
struct QCArgs   { PassData pass[18]; unsigned rfin[12]; };          // 912 B

__device__ __forceinline__ unsigned swz(unsigned m) { return m ^ ((m >> 6) & 63u); }

__global__ __launch_bounds__(TPB) void qsim_k(
    const float* __restrict__ x, const float* __restrict__ qp,
    const float* __restrict__ fcw, const float* __restrict__ fcb,
    float* __restrict__ out, int B, QCArgs A)
{
    __shared__ float2 st[DIM];          // swizzled state
    __shared__ float4 gmat[NL * NQ];    // (ur, ui, wr, wi) per gate
    __shared__ float cs[NQ], sn[NQ];
    __shared__ float zred[4 * NQ];
    __shared__ float zfin[NQ];

    const int tid = threadIdx.x;
    const int b = blockIdx.x;
    if (b >= B) return;

    // ---- gate coefficients (uniform across blocks): U = [[u, -conj(w)],[w, conj(u)]] ----
    if (tid < NL * NQ) {
        float phi = qp[tid * 3 + 0];
        float th  = qp[tid * 3 + 1];
        float om  = qp[tid * 3 + 2];
        float st_, ct, sa, ca, sb, cb;
        sincosf(0.5f * th, &st_, &ct);
        sincosf(0.5f * (phi + om), &sa, &ca);
        sincosf(0.5f * (phi - om), &sb, &cb);
        gmat[tid] = make_float4(ca * ct, -sa * ct, cb * st_, -sb * st_);
    }
    if (tid < NQ) {
        float s, c;
        sincosf(0.5f * x[b * NQ + tid], &s, &c);
        cs[tid] = c; sn[tid] = s;
    }
    __syncthreads();

    // ---- initial product state: bit p of index m <-> qubit 11-p ----
    {
        float hp = 1.0f;
        #pragma unroll
        for (int p = 4; p < 12; ++p)
            hp *= ((tid >> (p - 4)) & 1) ? sn[11 - p] : cs[11 - p];
        float lp[16];
        lp[0] = hp;
        #pragma unroll
        for (int p = 0; p < 4; ++p) {
            #pragma unroll
            for (int i = 0; i < (1 << p); ++i) {
                lp[i | (1 << p)] = lp[i] * sn[11 - p];
                lp[i] = lp[i] * cs[11 - p];
            }
        }
        #pragma unroll
        for (int k = 0; k < 16; ++k) {
            unsigned m = ((unsigned)tid << 4) | (unsigned)k;
            st[swz(m)] = make_float2(lp[k], 0.0f);
        }
    }

    float ar[16], ai[16];
    unsigned gbase = 0;

    // ---- 18 fused passes (4 Rot gates each); CNOT rings absorbed into masks ----
    #pragma unroll 1
    for (int p = 0; p < 18; ++p) {
        __syncthreads();
        const unsigned v0 = A.pass[p].v[0], v1 = A.pass[p].v[1];
        const unsigned v2 = A.pass[p].v[2], v3 = A.pass[p].v[3];

        unsigned g = (unsigned)tid;
        #pragma unroll
        for (int k = 0; k < 4; ++k) {
            unsigned lm = A.pass[p].lm[k];
            g = ((g & ~lm) << 1) | (g & lm);
        }
        const unsigned gs = swz(g);

        unsigned svo[16];
        #pragma unroll
        for (int s2 = 0; s2 < 16; ++s2) {
            unsigned vo = ((s2 & 1) ? v0 : 0u) ^ ((s2 & 2) ? v1 : 0u)
                        ^ ((s2 & 4) ? v2 : 0u) ^ ((s2 & 8) ? v3 : 0u);
            svo[s2] = swz(vo);
        }

        #pragma unroll
        for (int s2 = 0; s2 < 16; ++s2) {
            float2 a2 = st[gs ^ svo[s2]];
            ar[s2] = a2.x; ai[s2] = a2.y;
        }

        const int gb = (p / 3) * NQ + (p % 3) * 4;
        #pragma unroll
        for (int j = 0; j < 4; ++j) {
            float4 gq = gmat[gb + j];
            float ur = gq.x, ui = gq.y, wr = gq.z, wi = gq.w;
            unsigned pg = __popc(A.pass[p].r[j] & g) & 1u;
            unsigned sg = pg << 31;
            float uia = __uint_as_float(__float_as_uint(ui) ^ sg);
            float wra = __uint_as_float(__float_as_uint(wr) ^ sg ^ 0x80000000u);
            #pragma unroll
            for (int s2 = 0; s2 < 16; ++s2) {
                if (!(s2 & (1 << j))) {
                    const int sb2 = s2 | (1 << j);
                    float a0r = ar[s2],  a0i = ai[s2];
                    float a1r = ar[sb2], a1i = ai[sb2];
                    ar[s2]  = ur * a0r - uia * a0i + wra * a1r - wi * a1i;
                    ai[s2]  = ur * a0i + uia * a0r + wra * a1i + wi * a1r;
                    ar[sb2] = ur * a1r + uia * a1i - wra * a0r - wi * a0i;
                    ai[sb2] = ur * a1i - uia * a1r - wra * a0i + wi * a0r;
                }
            }
        }

        if (p < 17) {
            #pragma unroll
            for (int s2 = 0; s2 < 16; ++s2)
                st[gs ^ svo[s2]] = make_float2(ar[s2], ai[s2]);
        } else {
            gbase = g;
        }
    }

    // ---- PauliZ expvals from pass-17 registers ----
    float p2[16];
    #pragma unroll
    for (int s2 = 0; s2 < 16; ++s2) p2[s2] = ar[s2] * ar[s2] + ai[s2] * ai[s2];

    unsigned vo17[16];
    {
        const unsigned v0 = A.pass[17].v[0], v1 = A.pass[17].v[1];
        const unsigned v2 = A.pass[17].v[2], v3 = A.pass[17].v[3];
        #pragma unroll
        for (int s2 = 0; s2 < 16; ++s2)
            vo17[s2] = ((s2 & 1) ? v0 : 0u) ^ ((s2 & 2) ? v1 : 0u)
                     ^ ((s2 & 4) ? v2 : 0u) ^ ((s2 & 8) ? v3 : 0u);
    }

    float z[NQ];
    #pragma unroll
    for (int q = 0; q < NQ; ++q) {
        const unsigned rq = A.rfin[q];
        unsigned basebit = (unsigned)(__popc(rq & gbase) & 1) << 31;
        float acc = 0.0f;
        #pragma unroll
        for (int s2 = 0; s2 < 16; ++s2) {
            unsigned sbit = (unsigned)(__popc(rq & vo17[s2]) & 1) << 31;  // uniform
            acc += __uint_as_float(__float_as_uint(p2[s2]) ^ sbit);
        }
        z[q] = __uint_as_float(__float_as_uint(acc) ^ basebit);
    }

    // ---- reduce: wave butterfly, then cross-wave via LDS ----
    #pragma unroll
    for (int q = 0; q < NQ; ++q) {
        float v = z[q];
        #pragma unroll
        for (int o = 1; o < 64; o <<= 1) v += __shfl_xor(v, o, 64);
        z[q] = v;
    }
    const int lane = tid & 63, wv = tid >> 6;
    if (lane == 0) {
        #pragma unroll
        for (int q = 0; q < NQ; ++q) zred[wv * NQ + q] = z[q];
    }
    __syncthreads();
    if (tid < NQ)
        zfin[tid] = zred[tid] + zred[NQ + tid] + zred[2 * NQ + tid] + zred[3 * NQ + tid];
    __syncthreads();

    if (tid < NC) {
        float acc = fcb[tid];
        #pragma unroll
        for (int q = 0; q < NQ; ++q) acc += fcw[tid * NQ + q] * zfin[q];
        out[b * NC + tid] = acc;
    }
}

// ---------------- host: GF(2) circuit algebra ----------------
static void inv12(const unsigned Ain[12], unsigned Ai[12]) {
    unsigned M[12], I[12];
    for (int i = 0; i < 12; ++i) { M[i] = Ain[i]; I[i] = 1u << i; }
    for (int c = 0; c < 12; ++c) {
        int pr = -1;
        for (int r2 = c; r2 < 12; ++r2) if ((M[r2] >> c) & 1u) { pr = r2; break; }
        unsigned tm = M[c]; M[c] = M[pr]; M[pr] = tm;
        tm = I[c]; I[c] = I[pr]; I[pr] = tm;
        for (int r2 = 0; r2 < 12; ++r2)
            if (r2 != c && ((M[r2] >> c) & 1u)) { M[r2] ^= M[c]; I[r2] ^= I[c]; }
    }
    for (int i = 0; i < 12; ++i) Ai[i] = I[i];
}

extern "C" void kernel_launch(void* const* d_in, const int* in_sizes, int n_in,
                              void* d_out, int out_size, void* d_ws, size_t ws_size,
                              hipStream_t stream) {
    const float* x    = (const float*)d_in[0];
    const float* qp   = (const float*)d_in[1];
    const float* fc_w = (const float*)d_in[2];
    const float* fc_b = (const float*)d_in[3];
    float* out = (float*)d_out;
    int B = in_sizes[0] / NQ;

    QCArgs A;
    unsigned L[12];
    for (int i = 0; i < 12; ++i) L[i] = 1u << i;   // phys->logical map, rows over phys bits

    for (int l = 0; l < NL; ++l) {
        unsigned Linv[12];
        inv12(L, Linv);
        for (int m = 0; m < 3; ++m) {
            PassData& P = A.pass[l * 3 + m];
            for (int j = 0; j < 4; ++j) {
                int q = 4 * m + j;
                int bb = 11 - q;
                P.r[j] = L[bb];
                unsigned v = 0;
                for (int i = 0; i < 12; ++i) v |= ((Linv[i] >> bb) & 1u) << i;  // col bb
                P.v[j] = v;
            }
            // pivots (forward elimination, lowest bit first)
            unsigned w[4] = { P.v[0], P.v[1], P.v[2], P.v[3] };
            int piv[4];
            for (int j = 0; j < 4; ++j) {
                for (int k = 0; k < j; ++k)
                    if ((w[j] >> piv[k]) & 1u) w[j] ^= w[k];
                piv[j] = __builtin_ctz(w[j]);
            }
            // sort pivots ascending
            for (int a = 0; a < 4; ++a)
                for (int c = a + 1; c < 4; ++c)
                    if (piv[c] < piv[a]) { int t = piv[a]; piv[a] = piv[c]; piv[c] = t; }
            for (int k = 0; k < 4; ++k) P.lm[k] = (1u << piv[k]) - 1u;
        }
        // apply CNOT ring l (r = l+1), in application order: L <- C o L
        int rr = l + 1;
        for (int q = 0; q < 12; ++q) {
            int tq = (q + rr) % 12;
            int bc = 11 - q, bt = 11 - tq;
            L[bt] ^= L[bc];
        }
    }
    for (int q = 0; q < 12; ++q) A.rfin[q] = L[11 - q];

    qsim_k<<<B, TPB, 0, stream>>>(x, qp, fc_w, fc_b, out, B, A);
}

// Round 4
// 287.954 us; speedup vs baseline: 5.5501x; 1.3988x over previous
//
#include <hip/hip_runtime.h>

#define NQ 12
#define NL 6
#define NC 10
#define DIM 4096
#define TPB 256

typedef float v2f __attribute__((ext_vector_type(2)));

#if __has_builtin(__builtin_elementwise_fma)
#define FMA2(a, b, c) __builtin_elementwise_fma((a), (b), (c))
#else
#define FMA2(a, b, c) ((a) * (b) + (c))
#endif

__device__ __forceinline__ v2f splat2(float v) { v2f r; r.x = v; r.y = v; return r; }

struct PassData { unsigned v[4]; unsigned r[4]; unsigned lm[4]; };
struct QCArgs   { PassData pass[18]; unsigned rfin[12]; };

__device__ __forceinline__ unsigned swz(unsigned m) { return m ^ ((m >> 6) & 63u); }

__global__ __launch_bounds__(TPB) void qsim_k(
    const float* __restrict__ x, const float* __restrict__ qp,
    const float* __restrict__ fcw, const float* __restrict__ fcb,
    float* __restrict__ out, int B, QCArgs A)
{
    // [0,DIM): packed re (batch b0,b1); [DIM,2*DIM): packed im
    __shared__ v2f stv[2 * DIM];
    __shared__ float4 gmat[NL * NQ];
    __shared__ v2f csn[NQ], snn[NQ];
    __shared__ v2f zred[4 * NQ];
    __shared__ v2f zfin[NQ];

    const int tid = threadIdx.x;
    const int blk = blockIdx.x;
    const int b0 = blk * 2;
    const int b1 = blk * 2 + 1;

    // ---- gate coefficients (uniform across blocks): U00 = ur + i*ui, U01-ish via wr,wi ----
    if (tid < NL * NQ) {
        float phi = qp[tid * 3 + 0];
        float th  = qp[tid * 3 + 1];
        float om  = qp[tid * 3 + 2];
        float st_, ct, sa, ca, sb, cb;
        sincosf(0.5f * th, &st_, &ct);
        sincosf(0.5f * (phi + om), &sa, &ca);
        sincosf(0.5f * (phi - om), &sb, &cb);
        gmat[tid] = make_float4(ca * ct, -sa * ct, cb * st_, -sb * st_);
    }
    // packed trig for the two batch elements
    if (tid < 2 * NQ) {
        int half = tid / NQ;
        int q = tid - half * NQ;
        int bb = blk * 2 + half;
        float xx = (bb < B) ? x[bb * NQ + q] : 0.0f;
        float s, c;
        sincosf(0.5f * xx, &s, &c);
        if (half == 0) { csn[q].x = c; snn[q].x = s; }
        else           { csn[q].y = c; snn[q].y = s; }
    }
    __syncthreads();

    // ---- initial product state (both batch elems packed): bit p of m <-> qubit 11-p ----
    {
        v2f hp = splat2(1.0f);
        #pragma unroll
        for (int p = 4; p < 12; ++p)
            hp *= ((tid >> (p - 4)) & 1) ? snn[11 - p] : csn[11 - p];
        v2f lp[16];
        lp[0] = hp;
        #pragma unroll
        for (int p = 0; p < 4; ++p) {
            #pragma unroll
            for (int i = 0; i < (1 << p); ++i) {
                lp[i | (1 << p)] = lp[i] * snn[11 - p];
                lp[i] = lp[i] * csn[11 - p];
            }
        }
        #pragma unroll
        for (int k = 0; k < 16; ++k) {
            unsigned m = swz(((unsigned)tid << 4) | (unsigned)k);
            stv[m] = lp[k];
            stv[m + DIM] = splat2(0.0f);
        }
    }

    v2f aR[16], aI[16];
    unsigned gbase = 0;

    // ---- 18 fused passes (4 Rot gates each); CNOT rings absorbed into masks ----
    #pragma unroll 1
    for (int p = 0; p < 18; ++p) {
        __syncthreads();
        const unsigned v0 = A.pass[p].v[0], v1 = A.pass[p].v[1];
        const unsigned v2 = A.pass[p].v[2], v3 = A.pass[p].v[3];

        unsigned g = (unsigned)tid;
        #pragma unroll
        for (int k = 0; k < 4; ++k) {
            unsigned lm = A.pass[p].lm[k];
            g = ((g & ~lm) << 1) | (g & lm);
        }
        const unsigned gs = swz(g);

        unsigned svoS[16];
        #pragma unroll
        for (int s2 = 0; s2 < 16; ++s2) {
            unsigned vo = ((s2 & 1) ? v0 : 0u) ^ ((s2 & 2) ? v1 : 0u)
                        ^ ((s2 & 4) ? v2 : 0u) ^ ((s2 & 8) ? v3 : 0u);
            svoS[s2] = __builtin_amdgcn_readfirstlane(swz(vo));  // uniform -> SGPR
        }

        unsigned ad[16];
        #pragma unroll
        for (int s2 = 0; s2 < 16; ++s2) {
            ad[s2] = gs ^ svoS[s2];
            aR[s2] = stv[ad[s2]];
            aI[s2] = stv[ad[s2] + DIM];
        }

        const int gb = (p / 3) * NQ + (p % 3) * 4;
        #pragma unroll
        for (int j = 0; j < 4; ++j) {
            float4 gq = gmat[gb + j];
            unsigned sg = (unsigned)(__popc(A.pass[p].r[j] & g) & 1) << 31;
            float uia = __uint_as_float(__float_as_uint(gq.y) ^ sg);
            float wra = __uint_as_float(__float_as_uint(gq.z) ^ sg ^ 0x80000000u);
            const v2f ur2  = splat2(gq.x);
            const v2f uia2 = splat2(uia);
            const v2f wra2 = splat2(wra);
            const v2f wi2  = splat2(gq.w);
            #pragma unroll
            for (int s2 = 0; s2 < 16; ++s2) {
                if (!(s2 & (1 << j))) {
                    const int sb2 = s2 | (1 << j);
                    v2f a0r = aR[s2],  a0i = aI[s2];
                    v2f a1r = aR[sb2], a1i = aI[sb2];
                    aR[s2]  = FMA2(ur2, a0r, FMA2(-uia2, a0i, FMA2(wra2, a1r, -wi2 * a1i)));
                    aI[s2]  = FMA2(ur2, a0i, FMA2(uia2,  a0r, FMA2(wra2, a1i,  wi2 * a1r)));
                    aR[sb2] = FMA2(ur2, a1r, FMA2(uia2,  a1i, FMA2(-wra2, a0r, -wi2 * a0i)));
                    aI[sb2] = FMA2(ur2, a1i, FMA2(-uia2, a1r, FMA2(-wra2, a0i,  wi2 * a0r)));
                }
            }
        }

        if (p < 17) {
            #pragma unroll
            for (int s2 = 0; s2 < 16; ++s2) {
                stv[ad[s2]] = aR[s2];
                stv[ad[s2] + DIM] = aI[s2];
            }
        } else {
            gbase = g;
        }
    }

    // ---- PauliZ expvals (packed) from pass-17 registers ----
    v2f p2[16];
    #pragma unroll
    for (int s2 = 0; s2 < 16; ++s2) p2[s2] = FMA2(aR[s2], aR[s2], aI[s2] * aI[s2]);

    unsigned vo17[16];
    {
        const unsigned v0 = A.pass[17].v[0], v1 = A.pass[17].v[1];
        const unsigned v2 = A.pass[17].v[2], v3 = A.pass[17].v[3];
        #pragma unroll
        for (int s2 = 0; s2 < 16; ++s2)
            vo17[s2] = ((s2 & 1) ? v0 : 0u) ^ ((s2 & 2) ? v1 : 0u)
                     ^ ((s2 & 4) ? v2 : 0u) ^ ((s2 & 8) ? v3 : 0u);
    }

    v2f z[NQ];
    #pragma unroll
    for (int q = 0; q < NQ; ++q) {
        const unsigned rq = A.rfin[q];
        v2f acc = splat2(0.0f);
        #pragma unroll
        for (int s2 = 0; s2 < 16; ++s2) {
            float sf = (__popc(rq & vo17[s2]) & 1) ? -1.0f : 1.0f;  // uniform
            acc = FMA2(splat2(sf), p2[s2], acc);
        }
        float bf = (__popc(rq & gbase) & 1) ? -1.0f : 1.0f;
        z[q] = splat2(bf) * acc;
    }

    // ---- reduce: wave butterfly (per component), then cross-wave via LDS ----
    #pragma unroll
    for (int q = 0; q < NQ; ++q) {
        float vx = z[q].x, vy = z[q].y;
        #pragma unroll
        for (int o = 1; o < 64; o <<= 1) {
            vx += __shfl_xor(vx, o, 64);
            vy += __shfl_xor(vy, o, 64);
        }
        z[q].x = vx; z[q].y = vy;
    }
    const int lane = tid & 63, wv = tid >> 6;
    if (lane == 0) {
        #pragma unroll
        for (int q = 0; q < NQ; ++q) zred[wv * NQ + q] = z[q];
    }
    __syncthreads();
    if (tid < NQ)
        zfin[tid] = zred[tid] + zred[NQ + tid] + zred[2 * NQ + tid] + zred[3 * NQ + tid];
    __syncthreads();

    if (tid < NC) {
        v2f acc = splat2(fcb[tid]);
        #pragma unroll
        for (int q = 0; q < NQ; ++q) acc = FMA2(splat2(fcw[tid * NQ + q]), zfin[q], acc);
        out[b0 * NC + tid] = acc.x;
        if (b1 < B) out[b1 * NC + tid] = acc.y;
    }
}

// ---------------- host: GF(2) circuit algebra ----------------
static void inv12(const unsigned Ain[12], unsigned Ai[12]) {
    unsigned M[12], I[12];
    for (int i = 0; i < 12; ++i) { M[i] = Ain[i]; I[i] = 1u << i; }
    for (int c = 0; c < 12; ++c) {
        int pr = -1;
        for (int r2 = c; r2 < 12; ++r2) if ((M[r2] >> c) & 1u) { pr = r2; break; }
        unsigned tm = M[c]; M[c] = M[pr]; M[pr] = tm;
        tm = I[c]; I[c] = I[pr]; I[pr] = tm;
        for (int r2 = 0; r2 < 12; ++r2)
            if (r2 != c && ((M[r2] >> c) & 1u)) { M[r2] ^= M[c]; I[r2] ^= I[c]; }
    }
    for (int i = 0; i < 12; ++i) Ai[i] = I[i];
}

extern "C" void kernel_launch(void* const* d_in, const int* in_sizes, int n_in,
                              void* d_out, int out_size, void* d_ws, size_t ws_size,
                              hipStream_t stream) {
    const float* x    = (const float*)d_in[0];
    const float* qp   = (const float*)d_in[1];
    const float* fc_w = (const float*)d_in[2];
    const float* fc_b = (const float*)d_in[3];
    float* out = (float*)d_out;
    int B = in_sizes[0] / NQ;

    QCArgs A;
    unsigned L[12];
    for (int i = 0; i < 12; ++i) L[i] = 1u << i;   // phys->logical map, rows over phys bits

    for (int l = 0; l < NL; ++l) {
        unsigned Linv[12];
        inv12(L, Linv);
        for (int m = 0; m < 3; ++m) {
            PassData& P = A.pass[l * 3 + m];
            for (int j = 0; j < 4; ++j) {
                int q = 4 * m + j;
                int bb = 11 - q;
                P.r[j] = L[bb];
                unsigned v = 0;
                for (int i = 0; i < 12; ++i) v |= ((Linv[i] >> bb) & 1u) << i;  // col bb
                P.v[j] = v;
            }
            // pivots (forward elimination, lowest bit first)
            unsigned w[4] = { P.v[0], P.v[1], P.v[2], P.v[3] };
            int piv[4];
            for (int j = 0; j < 4; ++j) {
                for (int k = 0; k < j; ++k)
                    if ((w[j] >> piv[k]) & 1u) w[j] ^= w[k];
                piv[j] = __builtin_ctz(w[j]);
            }
            for (int a = 0; a < 4; ++a)
                for (int c = a + 1; c < 4; ++c)
                    if (piv[c] < piv[a]) { int t = piv[a]; piv[a] = piv[c]; piv[c] = t; }
            for (int k = 0; k < 4; ++k) P.lm[k] = (1u << piv[k]) - 1u;
        }
        // apply CNOT ring l (r = l+1): L <- C o L
        int rr = l + 1;
        for (int q = 0; q < 12; ++q) {
            int tq = (q + rr) % 12;
            int bc = 11 - q, bt = 11 - tq;
            L[bt] ^= L[bc];
        }
    }
    for (int q = 0; q < 12; ++q) A.rfin[q] = L[11 - q];

    int nblk = (B + 1) / 2;
    qsim_k<<<nblk, TPB, 0, stream>>>(x, qp, fc_w, fc_b, out, B, A);
}

// Round 5
// 262.469 us; speedup vs baseline: 6.0890x; 1.0971x over previous
//
#include <hip/hip_runtime.h>

#define NQ 12
#define NL 6
#define NC 10
#define DIM 4096
#define TPB 512
#define NPASS 24

typedef float v2f __attribute__((ext_vector_type(2)));
#define FMA2(a, b, c) __builtin_elementwise_fma((a), (b), (c))

__device__ __forceinline__ v2f splat2(float v) { v2f r; r.x = v; r.y = v; return r; }

struct PassA { unsigned short Acol[9]; unsigned short svo4[8]; unsigned short w[3]; };
struct QCArgs {
    PassA P[NPASS];
    unsigned short Gcol0[9];
    unsigned short vc0[8];
    unsigned short wq[NQ];
    unsigned char  tab[NQ];
};

__global__ __launch_bounds__(TPB, 4) void qsim_k(
    const float* __restrict__ x, const float* __restrict__ qp,
    const float* __restrict__ fcw, const float* __restrict__ fcb,
    float* __restrict__ out, int B, QCArgs K)
{
    __shared__ float4 stv[DIM];          // (re.b0, re.b1, im.b0, im.b1) per amp, layout T*m
    __shared__ float4 gmat[NL * NQ];     // (ur, ui, wr, wi)
    __shared__ v2f csn[NQ], snn[NQ];
    __shared__ v2f zred[8 * NQ];
    __shared__ v2f zfin[NQ];

    const unsigned tid = threadIdx.x;
    const int blk = blockIdx.x;
    const int b0 = blk * 2;
    const int b1 = blk * 2 + 1;

    // ---- gate coefficients (uniform across blocks) ----
    if (tid < NL * NQ) {
        float phi = qp[tid * 3 + 0];
        float th  = qp[tid * 3 + 1];
        float om  = qp[tid * 3 + 2];
        float st_, ct, sa, ca, sb, cb;
        sincosf(0.5f * th, &st_, &ct);
        sincosf(0.5f * (phi + om), &sa, &ca);
        sincosf(0.5f * (phi - om), &sb, &cb);
        gmat[tid] = make_float4(ca * ct, -sa * ct, cb * st_, -sb * st_);
    }
    if (tid < 2 * NQ) {
        int half = tid / NQ;
        int q = tid - half * NQ;
        int bb = blk * 2 + half;
        float xx = (bb < B) ? x[bb * NQ + q] : 0.0f;
        float s, c;
        sincosf(0.5f * xx, &s, &c);
        if (half == 0) { csn[q].x = c; snn[q].x = s; }
        else           { csn[q].y = c; snn[q].y = s; }
    }
    __syncthreads();

    // ---- init product state: compute logical base G and byte-address base A0 (pass-0 maps) ----
    {
        unsigned G = 0, A0 = 0;
        #pragma unroll
        for (int b2 = 0; b2 < 9; ++b2) {
            unsigned mneg = (unsigned)(-(int)((tid >> b2) & 1u));
            G  ^= mneg & (unsigned)K.Gcol0[b2];
            A0 ^= mneg & (unsigned)K.P[0].Acol[b2];
        }
        #pragma unroll
        for (int s = 0; s < 8; ++s) {
            unsigned idx = G ^ (unsigned)K.vc0[s];
            v2f amp = splat2(1.0f);
            #pragma unroll
            for (int p = 0; p < 12; ++p)
                amp *= ((idx >> p) & 1) ? snn[11 - p] : csn[11 - p];
            unsigned ad0 = A0 ^ (unsigned)K.P[0].svo4[s];
            *(float4*)((char*)stv + ad0) = make_float4(amp.x, amp.y, 0.0f, 0.0f);
        }
    }

    v2f aR[8], aI[8];

    // ---- 24 passes, 3 gates each; in-place per-thread cosets; 1 barrier/pass ----
    #pragma unroll 1
    for (int k = 0; k < NPASS; ++k) {
        __syncthreads();
        const PassA& P = K.P[k];

        unsigned A = 0;
        #pragma unroll
        for (int b2 = 0; b2 < 9; ++b2) {
            unsigned mneg = (unsigned)(-(int)((tid >> b2) & 1u));
            A ^= mneg & (unsigned)P.Acol[b2];
        }

        unsigned ad[8];
        #pragma unroll
        for (int s = 0; s < 8; ++s) {
            ad[s] = A ^ (unsigned)P.svo4[s];
            float4 f4 = *(const float4*)((const char*)stv + ad[s]);
            aR[s].x = f4.x; aR[s].y = f4.y;
            aI[s].x = f4.z; aI[s].y = f4.w;
        }

        const int gbase = (k >> 2) * NQ + (k & 3) * 3;
        #pragma unroll
        for (int j = 0; j < 3; ++j) {
            float4 gq = gmat[gbase + j];
            unsigned sg = (unsigned)(__popc((unsigned)P.w[j] & tid) & 1) << 31;
            float uia = __uint_as_float(__float_as_uint(gq.y) ^ sg);
            float wra = __uint_as_float(__float_as_uint(gq.z) ^ sg ^ 0x80000000u);
            const v2f ur2  = splat2(gq.x);
            const v2f uia2 = splat2(uia);
            const v2f wra2 = splat2(wra);
            const v2f wi2  = splat2(gq.w);
            #pragma unroll
            for (int s = 0; s < 8; ++s) {
                if (!(s & (1 << j))) {
                    const int sb = s | (1 << j);
                    v2f a0r = aR[s],  a0i = aI[s];
                    v2f a1r = aR[sb], a1i = aI[sb];
                    aR[s]  = FMA2(ur2, a0r, FMA2(-uia2, a0i, FMA2(wra2, a1r, -wi2 * a1i)));
                    aI[s]  = FMA2(ur2, a0i, FMA2(uia2,  a0r, FMA2(wra2, a1i,  wi2 * a1r)));
                    aR[sb] = FMA2(ur2, a1r, FMA2(uia2,  a1i, FMA2(-wra2, a0r, -wi2 * a0i)));
                    aI[sb] = FMA2(ur2, a1i, FMA2(-uia2, a1r, FMA2(-wra2, a0i,  wi2 * a0r)));
                }
            }
        }

        if (k < NPASS - 1) {
            #pragma unroll
            for (int s = 0; s < 8; ++s)
                *(float4*)((char*)stv + ad[s]) =
                    make_float4(aR[s].x, aR[s].y, aI[s].x, aI[s].y);
        }
    }

    // ---- PauliZ expvals from pass-23 registers ----
    v2f p2[8];
    #pragma unroll
    for (int s = 0; s < 8; ++s) p2[s] = FMA2(aR[s], aR[s], aI[s] * aI[s]);

    v2f z[NQ];
    #pragma unroll
    for (int q = 0; q < NQ; ++q) {
        float base = (__popc((unsigned)K.wq[q] & tid) & 1) ? -1.0f : 1.0f;
        v2f acc = splat2(0.0f);
        #pragma unroll
        for (int s = 0; s < 8; ++s) {
            float sgn = ((K.tab[q] >> s) & 1) ? -base : base;
            acc = FMA2(splat2(sgn), p2[s], acc);
        }
        z[q] = acc;
    }

    #pragma unroll
    for (int q = 0; q < NQ; ++q) {
        float vx = z[q].x, vy = z[q].y;
        #pragma unroll
        for (int o = 1; o < 64; o <<= 1) {
            vx += __shfl_xor(vx, o, 64);
            vy += __shfl_xor(vy, o, 64);
        }
        z[q].x = vx; z[q].y = vy;
    }
    const int lane = tid & 63, wv = tid >> 6;
    if (lane == 0) {
        #pragma unroll
        for (int q = 0; q < NQ; ++q) zred[wv * NQ + q] = z[q];
    }
    __syncthreads();
    if (tid < NQ) {
        v2f acc = zred[tid];
        #pragma unroll
        for (int w2 = 1; w2 < 8; ++w2) acc += zred[w2 * NQ + tid];
        zfin[tid] = acc;
    }
    __syncthreads();

    if (tid < NC) {
        v2f acc = splat2(fcb[tid]);
        #pragma unroll
        for (int q = 0; q < NQ; ++q) acc = FMA2(splat2(fcw[tid * NQ + q]), zfin[q], acc);
        out[b0 * NC + tid] = acc.x;
        if (b1 < B) out[b1 * NC + tid] = acc.y;
    }
}

// ---------------- host: GF(2) circuit algebra + conflict-free layout search ----------------
static void inv12(const unsigned Ain[12], unsigned Ai[12]) {
    unsigned M[12], I[12];
    for (int i = 0; i < 12; ++i) { M[i] = Ain[i]; I[i] = 1u << i; }
    for (int c = 0; c < 12; ++c) {
        int pr = -1;
        for (int r2 = c; r2 < 12; ++r2) if ((M[r2] >> c) & 1u) { pr = r2; break; }
        unsigned tm = M[c]; M[c] = M[pr]; M[pr] = tm;
        tm = I[c]; I[c] = I[pr]; I[pr] = tm;
        for (int r2 = 0; r2 < 12; ++r2)
            if (r2 != c && ((M[r2] >> c) & 1u)) { M[r2] ^= M[c]; I[r2] ^= I[c]; }
    }
    for (int i = 0; i < 12; ++i) Ai[i] = I[i];
}

static unsigned lcg(unsigned& s) { s = s * 1664525u + 1013904223u; return s >> 8; }
static int pc(unsigned v) { return __builtin_popcount(v); }

static int rank_rows(const unsigned* rows, int n) {
    unsigned ech[16], low[16]; int rk = 0;
    for (int i = 0; i < n; ++i) {
        unsigned v = rows[i];
        for (int k2 = 0; k2 < rk; ++k2) if (v & low[k2]) v ^= ech[k2];
        if (v) { ech[rk] = v; low[rk] = v & (0u - v); ++rk; }
    }
    return rk;
}

extern "C" void kernel_launch(void* const* d_in, const int* in_sizes, int n_in,
                              void* d_out, int out_size, void* d_ws, size_t ws_size,
                              hipStream_t stream) {
    const float* x    = (const float*)d_in[0];
    const float* qp   = (const float*)d_in[1];
    const float* fc_w = (const float*)d_in[2];
    const float* fc_b = (const float*)d_in[3];
    float* out = (float*)d_out;
    int B = in_sizes[0] / NQ;

    QCArgs K;
    unsigned L[12];
    for (int i = 0; i < 12; ++i) L[i] = 1u << i;

    static unsigned gcolAll[NPASS][9];
    static unsigned vcAll[NPASS][8];

    for (int l = 0; l < NL; ++l) {
        unsigned Linv[12];
        inv12(L, Linv);
        for (int m = 0; m < 4; ++m) {
            int k = l * 4 + m;
            unsigned v[3], r[3];
            for (int j = 0; j < 3; ++j) {
                int q = 3 * m + j, bb = 11 - q;
                r[j] = L[bb];
                unsigned vv = 0;
                for (int i = 0; i < 12; ++i) vv |= ((Linv[i] >> bb) & 1u) << i;
                v[j] = vv;
            }
            // pivots of reduced {v0,v1,v2}
            unsigned w[3] = { v[0], v[1], v[2] };
            int piv[3];
            for (int j = 0; j < 3; ++j) {
                for (int k2 = 0; k2 < j; ++k2)
                    if ((w[j] >> piv[k2]) & 1u) w[j] ^= w[k2];
                piv[j] = __builtin_ctz(w[j]);
            }
            bool ispiv[12] = {};
            for (int j = 0; j < 3; ++j) ispiv[piv[j]] = true;
            int c = 0;
            for (int pos = 0; pos < 12; ++pos)
                if (!ispiv[pos]) gcolAll[k][c++] = 1u << pos;
            for (int s = 0; s < 8; ++s) {
                unsigned vc = 0;
                for (int j = 0; j < 3; ++j) if ((s >> j) & 1) vc ^= v[j];
                vcAll[k][s] = vc;
            }
            for (int j = 0; j < 3; ++j) {
                unsigned ws = 0;
                for (int b = 0; b < 9; ++b) ws |= (unsigned)(pc(r[j] & gcolAll[k][b]) & 1) << b;
                K.P[k].w[j] = (unsigned short)ws;
            }
        }
        int rr = l + 1;
        for (int q = 0; q < 12; ++q) {
            int tq = (q + rr) % 12;
            L[11 - tq] ^= L[11 - q];
        }
    }
    unsigned rfin[12];
    for (int q = 0; q < 12; ++q) rfin[q] = L[11 - q];

    // ---- search invertible T with low-3 rows rank-3 on every pass's lane subspace ----
    unsigned Trow[12];
    {
        unsigned seed = 0x1234567u;
        bool found = false;
        for (int att = 0; att < 50000 && !found; ++att) {
            for (int j = 0; j < 3; ++j) Trow[j] = lcg(seed) & 4095u;
            bool ok = true;
            for (int k = 0; k < NPASS && ok; ++k) {
                unsigned m3[3];
                for (int j = 0; j < 3; ++j) {
                    unsigned mm = 0;
                    for (int b = 0; b < 6; ++b)
                        mm |= (unsigned)(pc(Trow[j] & gcolAll[k][b]) & 1) << b;
                    m3[j] = mm;
                }
                ok = (rank_rows(m3, 3) == 3);
            }
            if (!ok) continue;
            // extend to full-rank 12x12
            unsigned ech[12], low[12]; int rk = 0;
            auto addrow = [&](unsigned vr) -> bool {
                unsigned vv = vr;
                for (int i = 0; i < rk; ++i) if (vv & low[i]) vv ^= ech[i];
                if (!vv) return false;
                ech[rk] = vv; low[rk] = vv & (0u - vv); ++rk;
                return true;
            };
            addrow(Trow[0]); addrow(Trow[1]); addrow(Trow[2]);
            int idx = 3, tries = 0;
            while (idx < 12 && tries < 8000) {
                unsigned rr2 = lcg(seed) & 4095u;
                if (addrow(rr2)) Trow[idx++] = rr2;
                ++tries;
            }
            if (idx == 12) found = true;
        }
        if (!found) for (int i = 0; i < 12; ++i) Trow[i] = 1u << i;  // correct, just slower
    }
    auto Tmap = [&](unsigned m) -> unsigned {
        unsigned o = 0;
        for (int i = 0; i < 12; ++i) o |= (unsigned)(pc(Trow[i] & m) & 1) << i;
        return o;
    };

    for (int k = 0; k < NPASS; ++k) {
        for (int b = 0; b < 9; ++b)
            K.P[k].Acol[b] = (unsigned short)(Tmap(gcolAll[k][b]) << 4);
        for (int s = 0; s < 8; ++s)
            K.P[k].svo4[s] = (unsigned short)(Tmap(vcAll[k][s]) << 4);
    }
    for (int b = 0; b < 9; ++b) K.Gcol0[b] = (unsigned short)gcolAll[0][b];
    for (int s = 0; s < 8; ++s) K.vc0[s] = (unsigned short)vcAll[0][s];
    for (int q = 0; q < 12; ++q) {
        unsigned ws = 0;
        for (int b = 0; b < 9; ++b) ws |= (unsigned)(pc(rfin[q] & gcolAll[NPASS - 1][b]) & 1) << b;
        K.wq[q] = (unsigned short)ws;
        unsigned tb = 0;
        for (int s = 0; s < 8; ++s) tb |= (unsigned)(pc(rfin[q] & vcAll[NPASS - 1][s]) & 1) << s;
        K.tab[q] = (unsigned char)tb;
    }

    int nblk = (B + 1) / 2;
    qsim_k<<<nblk, TPB, 0, stream>>>(x, qp, fc_w, fc_b, out, B, K);
}